// Round 13
// baseline (1716.164 us; speedup 1.0000x reference)
//
#include <hip/hip_runtime.h>
#include <hip/hip_bf16.h>
#include <math.h>

#define N_NODES 100000
#define N_EDGES 3200000
#define N_GRAPHS 16
#define C 64
#define L 6
#define H 32
#define EPS 1e-5f
#define NPARTS 4
#define PART_DIV 25000
#define NBUCKETS (N_NODES * NPARTS)  // 400000

static const int SCAN_BLOCKS = (NBUCKETS + 1023) / 1024;  // 391

__device__ __forceinline__ float gelu_exact(float x) {
    return 0.5f * x * (1.0f + erff(x * 0.70710678118654752440f));
}

__device__ __forceinline__ float wave_sum64(float v) {
#pragma unroll
    for (int m = 32; m >= 1; m >>= 1) v += __shfl_xor(v, m, 64);
    return v;
}

// sum over aligned 32-lane subgroup (masks <=16 stay inside the subgroup)
__device__ __forceinline__ float sum32(float v) {
#pragma unroll
    for (int m = 16; m >= 1; m >>= 1) v += __shfl_xor(v, m, 64);
    return v;
}

__device__ __forceinline__ unsigned short f32_to_bf16_rne(float f) {
    unsigned int u = __float_as_uint(f);
    u = (u + 0x7FFFu + ((u >> 16) & 1u)) >> 16;
    return (unsigned short)u;
}

// accumulate 8 bf16 channels (packed in uint4) into two float4s
#define ACC8(a0, a1, u)                                   \
    {                                                     \
        a0.x += __uint_as_float((u).x << 16);             \
        a0.y += __uint_as_float((u).x & 0xFFFF0000u);     \
        a0.z += __uint_as_float((u).y << 16);             \
        a0.w += __uint_as_float((u).y & 0xFFFF0000u);     \
        a1.x += __uint_as_float((u).z << 16);             \
        a1.y += __uint_as_float((u).z & 0xFFFF0000u);     \
        a1.z += __uint_as_float((u).w << 16);             \
        a1.w += __uint_as_float((u).w & 0xFFFF0000u);     \
    }

// ---------------- CSR build (sub-bucketed by src partition) ----------------

__global__ void k_count(const int* __restrict__ src, const int* __restrict__ dst,
                        int* __restrict__ degc, int* __restrict__ epos) {
    int i = blockIdx.x * blockDim.x + threadIdx.x;
    int stride = gridDim.x * blockDim.x;
    for (int e = i; e < N_EDGES; e += stride) {
        int part = src[e] / PART_DIV;
        int pos = __hip_atomic_fetch_add(&degc[dst[e] * NPARTS + part], 1,
                                         __ATOMIC_RELAXED, __HIP_MEMORY_SCOPE_AGENT);
        epos[e] = pos;
    }
}

__global__ __launch_bounds__(256) void k_scan1(const int* __restrict__ degc,
                                               int* __restrict__ scanned,
                                               int* __restrict__ bsum) {
    __shared__ int sc[2][256];
    int tid = threadIdx.x;
    int base = blockIdx.x * 1024 + tid * 4;
    int c0 = (base + 0 < NBUCKETS) ? degc[base + 0] : 0;
    int c1 = (base + 1 < NBUCKETS) ? degc[base + 1] : 0;
    int c2 = (base + 2 < NBUCKETS) ? degc[base + 2] : 0;
    int c3 = (base + 3 < NBUCKETS) ? degc[base + 3] : 0;
    int p0 = c0, p1 = p0 + c1, p2 = p1 + c2, p3 = p2 + c3;
    sc[0][tid] = p3;
    __syncthreads();
    int pb = 0;
    for (int offd = 1; offd < 256; offd <<= 1) {
        int v = sc[pb][tid];
        if (tid >= offd) v += sc[pb][tid - offd];
        sc[pb ^ 1][tid] = v;
        __syncthreads();
        pb ^= 1;
    }
    int incl = sc[pb][tid];
    int exth = incl - p3;
    if (base + 0 < NBUCKETS) scanned[base + 0] = exth + p0;
    if (base + 1 < NBUCKETS) scanned[base + 1] = exth + p1;
    if (base + 2 < NBUCKETS) scanned[base + 2] = exth + p2;
    if (base + 3 < NBUCKETS) scanned[base + 3] = exth + p3;
    if (tid == 255) bsum[blockIdx.x] = incl;
}

__global__ void k_scan2(const int* __restrict__ bsum, int* __restrict__ boff,
                        int* __restrict__ rowst) {
    int run = 0;
    for (int b = 0; b < SCAN_BLOCKS; ++b) { boff[b] = run; run += bsum[b]; }
    rowst[NBUCKETS] = run;  // == N_EDGES
}

__global__ void k_scan3(const int* __restrict__ degc, const int* __restrict__ scanned,
                        const int* __restrict__ boff, int* __restrict__ rowst) {
    int i = blockIdx.x * blockDim.x + threadIdx.x;
    if (i < NBUCKETS) rowst[i] = boff[i >> 10] + scanned[i] - degc[i];
}

__global__ void k_fill(const int* __restrict__ src, const int* __restrict__ dst,
                       const int* __restrict__ rowst, const int* __restrict__ epos,
                       int* __restrict__ esrc) {
    int i = blockIdx.x * blockDim.x + threadIdx.x;
    int stride = gridDim.x * blockDim.x;
    for (int e = i; e < N_EDGES; e += stride) {
        int s = src[e];
        int part = s / PART_DIV;
        esrc[rowst[dst[e] * NPARTS + part] + epos[e]] = s;
    }
}

// x -> bf16 shadow of h
__global__ void k_cvt(const float* __restrict__ x, unsigned short* __restrict__ hbf) {
    int i = blockIdx.x * blockDim.x + threadIdx.x;
    int stride = gridDim.x * blockDim.x;
    for (int k = i; k < N_NODES * C / 4; k += stride) {
        float4 v = ((const float4*)x)[k];
        ushort4 o;
        o.x = f32_to_bf16_rne(v.x);
        o.y = f32_to_bf16_rne(v.y);
        o.z = f32_to_bf16_rne(v.z);
        o.w = f32_to_bf16_rne(v.w);
        ((ushort4*)hbf)[k] = o;
    }
}

// ---------------- per-layer: mean aggregation, PHASE-SEPARATED by src part --
// One launch per src partition p: every wave gathers only edges whose src is
// in [25000p, 25000(p+1)) -- a 3.2MB bf16 slice that fits each XCD's 4MB L2.
// The kernel boundary is the phase barrier the round-5 experiment lacked.
// Partial sums accumulate into agg (f32); the last part divides by degree.

template <bool FIRST, bool LAST>
__global__ __launch_bounds__(256) void k_aggp(const unsigned short* __restrict__ hbf,
                                              const int* __restrict__ rowst,
                                              const int* __restrict__ esrc,
                                              float* __restrict__ agg,
                                              int part) {
    const uint4* __restrict__ hb4 = (const uint4*)hbf;  // row n = hb4[n*8 + co]
    int wave = threadIdx.x >> 6, lane = threadIdx.x & 63;
    int n = blockIdx.x * 4 + wave;
    if (n >= N_NODES) return;
    int s0 = rowst[n * NPARTS + part], s1 = rowst[n * NPARTS + part + 1];
    int esub = lane >> 3;   // 0..7 edge sub-index
    int co = lane & 7;      // channel oct (16B = 8 bf16)
    float4 accA0 = make_float4(0.f, 0.f, 0.f, 0.f), accA1 = accA0;
    float4 accB0 = accA0, accB1 = accA0;
    int j = s0;
    for (; j + 16 <= s1; j += 16) {
        int iA = esrc[j + 0 + esub];
        int iB = esrc[j + 8 + esub];
        uint4 a = hb4[(size_t)iA * 8 + co];
        uint4 b = hb4[(size_t)iB * 8 + co];
        ACC8(accA0, accA1, a);
        ACC8(accB0, accB1, b);
    }
    for (; j + 8 <= s1; j += 8) {
        int s = esrc[j + esub];
        uint4 a = hb4[(size_t)s * 8 + co];
        ACC8(accA0, accA1, a);
    }
    if (j < s1) {  // 1..7 leftover edges, predicated
        int jj = j + esub;
        bool v = jj < s1;
        int s = v ? esrc[jj] : 0;
        uint4 a = hb4[(size_t)s * 8 + co];
        if (!v) { a.x = 0; a.y = 0; a.z = 0; a.w = 0; }
        ACC8(accB0, accB1, a);
    }
    accA0.x += accB0.x; accA0.y += accB0.y; accA0.z += accB0.z; accA0.w += accB0.w;
    accA1.x += accB1.x; accA1.y += accB1.y; accA1.z += accB1.z; accA1.w += accB1.w;
    // reduce across the 8 edge sub-groups (lanes differing in bits 3,4,5)
#pragma unroll
    for (int m = 8; m <= 32; m <<= 1) {
        accA0.x += __shfl_xor(accA0.x, m, 64);
        accA0.y += __shfl_xor(accA0.y, m, 64);
        accA0.z += __shfl_xor(accA0.z, m, 64);
        accA0.w += __shfl_xor(accA0.w, m, 64);
        accA1.x += __shfl_xor(accA1.x, m, 64);
        accA1.y += __shfl_xor(accA1.y, m, 64);
        accA1.z += __shfl_xor(accA1.z, m, 64);
        accA1.w += __shfl_xor(accA1.w, m, 64);
    }
    if (lane < 8) {
        float4* dst = ((float4*)agg) + (size_t)n * 16 + co * 2;
        float4 r0 = accA0, r1 = accA1;
        if (!FIRST) {
            float4 p0 = dst[0], p1 = dst[1];
            r0.x += p0.x; r0.y += p0.y; r0.z += p0.z; r0.w += p0.w;
            r1.x += p1.x; r1.y += p1.y; r1.z += p1.z; r1.w += p1.w;
        }
        if (LAST) {
            int cnt = rowst[n * NPARTS + NPARTS] - rowst[n * NPARTS];
            float inv = 1.0f / (float)max(cnt, 1);
            r0.x *= inv; r0.y *= inv; r0.z *= inv; r0.w *= inv;
            r1.x *= inv; r1.y *= inv; r1.z *= inv; r1.w *= inv;
        }
        dst[0] = r0;
        dst[1] = r1;
    }
}

// ---------------- per-layer: fused GEMM+GELU+LN+residual ----------------
// One wave per node, BOTH GEMMs in-wave (Wl+Wr columns in 128 VGPRs),
// wave-private LDS rows, no block barriers. Also writes the bf16 shadow.

__global__ __launch_bounds__(256) void k_sage(const float* __restrict__ h,
                                              const float* __restrict__ agg,
                                              const float* __restrict__ Wl,
                                              const float* __restrict__ bl,
                                              const float* __restrict__ Wr,
                                              const float* __restrict__ gn,
                                              const float* __restrict__ bn,
                                              float* __restrict__ hout,
                                              unsigned short* __restrict__ hbf) {
    __shared__ float rowA[4][C];
    __shared__ float rowH[4][C];
    int lane = threadIdx.x & 63;
    int wave = threadIdx.x >> 6;
    float wl[C], wr[C];
#pragma unroll
    for (int j = 0; j < C; ++j) wl[j] = Wl[j * C + lane];  // column `lane`
#pragma unroll
    for (int j = 0; j < C; ++j) wr[j] = Wr[j * C + lane];
    float blc = bl[lane], gc = gn[lane], bc = bn[lane];

    const float4* a4 = (const float4*)rowA[wave];
    const float4* h4s = (const float4*)rowH[wave];
    for (int n = blockIdx.x * 4 + wave; n < N_NODES; n += 2048 * 4) {
        float av = agg[(size_t)n * C + lane];
        float hv = h[(size_t)n * C + lane];
        rowA[wave][lane] = av;
        rowH[wave][lane] = hv;
        float acc = blc;
#pragma unroll
        for (int k4 = 0; k4 < C / 4; ++k4) {
            float4 a = a4[k4];
            float4 b = h4s[k4];
            acc += a.x * wl[4 * k4 + 0] + a.y * wl[4 * k4 + 1] +
                   a.z * wl[4 * k4 + 2] + a.w * wl[4 * k4 + 3];
            acc += b.x * wr[4 * k4 + 0] + b.y * wr[4 * k4 + 1] +
                   b.z * wr[4 * k4 + 2] + b.w * wr[4 * k4 + 3];
        }
        float f = gelu_exact(acc);
        float mu = wave_sum64(f) * (1.0f / C);
        float d = f - mu;
        float var = wave_sum64(d * d) * (1.0f / C);
        float y = d * rsqrtf(var + EPS) * gc + bc;
        float res = y + hv;  // residual
        hout[(size_t)n * C + lane] = res;
        hbf[(size_t)n * C + lane] = f32_to_bf16_rne(res);
    }
}

// ---------------- pooling (segment_max) ----------------

__global__ __launch_bounds__(256) void k_pool_partial(const float* __restrict__ h,
                                                      const int* __restrict__ batch,
                                                      float* __restrict__ partial) {
    __shared__ float pp[4][N_GRAPHS][C];
    int lane = threadIdx.x & 63, wave = threadIdx.x >> 6;
#pragma unroll
    for (int g = 0; g < N_GRAPHS; ++g) pp[wave][g][lane] = -INFINITY;
    int chunk = (N_NODES + gridDim.x - 1) / gridDim.x;
    int start = blockIdx.x * chunk;
    int end = min(start + chunk, N_NODES);
    for (int n = start + wave; n < end; n += 4) {
        int g = batch[n];
        float v = h[(size_t)n * C + lane];
        pp[wave][g][lane] = fmaxf(pp[wave][g][lane], v);
    }
    __syncthreads();
    for (int g = wave * 4; g < wave * 4 + 4; ++g) {
        float m = fmaxf(fmaxf(pp[0][g][lane], pp[1][g][lane]),
                        fmaxf(pp[2][g][lane], pp[3][g][lane]));
        partial[(size_t)blockIdx.x * (N_GRAPHS * C) + g * C + lane] = m;
    }
}

__global__ void k_pool_final(const float* __restrict__ partial, float* __restrict__ pooled) {
    int t = threadIdx.x;  // 1024 threads = 16*64
    float m = -INFINITY;
    for (int b = 0; b < 128; ++b) m = fmaxf(m, partial[b * (N_GRAPHS * C) + t]);
    pooled[t] = m;
}

// ---------------- MLP head ----------------

__global__ __launch_bounds__(512) void k_head(const float* __restrict__ pooled,
                                              const float* __restrict__ W0,
                                              const float* __restrict__ b0,
                                              const float* __restrict__ g0,
                                              const float* __restrict__ bn0,
                                              const float* __restrict__ W,
                                              const float* __restrict__ bb,
                                              const float* __restrict__ gg,
                                              const float* __restrict__ bnn,
                                              const float* __restrict__ hW,
                                              const float* __restrict__ hb,
                                              float* __restrict__ out) {
    __shared__ float ps[N_GRAPHS][C];
    __shared__ float zs[N_GRAPHS][H];
    int t = threadIdx.x;
    for (int i = t; i < N_GRAPHS * C; i += 512) ps[i >> 6][i & 63] = pooled[i];
    __syncthreads();
    int g = t >> 5, j = t & 31;
    float acc = b0[j];
#pragma unroll 8
    for (int k = 0; k < C; ++k) acc += ps[g][k] * W0[k * H + j];
    acc = gelu_exact(acc);
    float mu = sum32(acc) * (1.0f / H);
    float d = acc - mu;
    float var = sum32(d * d) * (1.0f / H);
    float z = d * rsqrtf(var + EPS) * g0[j] + bn0[j];
    zs[g][j] = z;
    __syncthreads();
    for (int i = 0; i < 3; ++i) {
        float a = bb[i * H + j];
#pragma unroll 8
        for (int k = 0; k < H; ++k) a += zs[g][k] * W[i * H * H + k * H + j];
        a = gelu_exact(a);
        float mu2 = sum32(a) * (1.0f / H);
        float d2 = a - mu2;
        float v2 = sum32(d2 * d2) * (1.0f / H);
        float tt = d2 * rsqrtf(v2 + EPS) * gg[i * H + j] + bnn[i * H + j];
        float zn = tt + zs[g][j];
        __syncthreads();
        zs[g][j] = zn;
        __syncthreads();
    }
    float hv = zs[g][j] * hW[j];
    hv = sum32(hv);
    if (j == 0) out[g] = hv + hb[0];
}

// ---------------- launch ----------------

extern "C" void kernel_launch(void* const* d_in, const int* in_sizes, int n_in,
                              void* d_out, int out_size, void* d_ws, size_t ws_size,
                              hipStream_t stream) {
    const float* x    = (const float*)d_in[0];
    const int* edge   = (const int*)d_in[1];
    const int* batch  = (const int*)d_in[2];
    const float* sWl  = (const float*)d_in[3];
    const float* sbl  = (const float*)d_in[4];
    const float* sWr  = (const float*)d_in[5];
    const float* sg   = (const float*)d_in[6];
    const float* sb   = (const float*)d_in[7];
    const float* W0   = (const float*)d_in[8];
    const float* b0   = (const float*)d_in[9];
    const float* g0   = (const float*)d_in[10];
    const float* bn0  = (const float*)d_in[11];
    const float* mW   = (const float*)d_in[12];
    const float* mb   = (const float*)d_in[13];
    const float* mg   = (const float*)d_in[14];
    const float* mbn  = (const float*)d_in[15];
    const float* hW   = (const float*)d_in[16];
    const float* hb   = (const float*)d_in[17];
    float* out = (float*)d_out;

    const int* esrc_in = edge;            // edge_index[0]
    const int* edst_in = edge + N_EDGES;  // edge_index[1]

    char* ws = (char*)d_ws;
    size_t off = 0;
    auto alloc = [&](size_t bytes) {
        void* p = ws + off;
        off = (off + bytes + 1023) & ~(size_t)1023;
        return p;
    };
    float* h      = (float*)alloc((size_t)N_NODES * C * 4);
    float* agg    = (float*)alloc((size_t)N_NODES * C * 4);
    unsigned short* hbf = (unsigned short*)alloc((size_t)N_NODES * C * 2);
    int* degc     = (int*)alloc((size_t)NBUCKETS * 4);
    int* scanned  = (int*)alloc((size_t)NBUCKETS * 4);
    int* rowst    = (int*)alloc((size_t)(NBUCKETS + 1) * 4);
    int* esrc     = (int*)alloc((size_t)N_EDGES * 4);
    int* epos     = (int*)alloc((size_t)N_EDGES * 4);
    int* bsum     = (int*)alloc(512 * 4);
    int* boff     = (int*)alloc(512 * 4);
    float* part   = (float*)alloc((size_t)128 * N_GRAPHS * C * 4);
    float* pooled = (float*)alloc((size_t)N_GRAPHS * C * 4);
    (void)ws_size;

    hipMemsetAsync(degc, 0, (size_t)NBUCKETS * 4, stream);

    k_count<<<2048, 256, 0, stream>>>(esrc_in, edst_in, degc, epos);
    k_cvt<<<1600, 256, 0, stream>>>(x, hbf);
    k_scan1<<<SCAN_BLOCKS, 256, 0, stream>>>(degc, scanned, bsum);
    k_scan2<<<1, 1, 0, stream>>>(bsum, boff, rowst);
    k_scan3<<<(NBUCKETS + 255) / 256, 256, 0, stream>>>(degc, scanned, boff, rowst);
    k_fill<<<2048, 256, 0, stream>>>(esrc_in, edst_in, rowst, epos, esrc);

    const int AGG_BLOCKS = N_NODES / 4;  // 25000
    for (int i = 0; i < L; ++i) {
        k_aggp<true, false><<<AGG_BLOCKS, 256, 0, stream>>>(hbf, rowst, esrc, agg, 0);
        k_aggp<false, false><<<AGG_BLOCKS, 256, 0, stream>>>(hbf, rowst, esrc, agg, 1);
        k_aggp<false, false><<<AGG_BLOCKS, 256, 0, stream>>>(hbf, rowst, esrc, agg, 2);
        k_aggp<false, true><<<AGG_BLOCKS, 256, 0, stream>>>(hbf, rowst, esrc, agg, 3);
        k_sage<<<2048, 256, 0, stream>>>(i == 0 ? x : h, agg,
                                         sWl + (size_t)i * C * C, sbl + (size_t)i * C,
                                         sWr + (size_t)i * C * C, sg + (size_t)i * C,
                                         sb + (size_t)i * C, h, hbf);
    }

    k_pool_partial<<<128, 256, 0, stream>>>(h, batch, part);
    k_pool_final<<<1, 1024, 0, stream>>>(part, pooled);
    k_head<<<1, 512, 0, stream>>>(pooled, W0, b0, g0, bn0, mW, mb, mg, mbn, hW, hb, out);
}